// Round 4
// baseline (67.301 us; speedup 1.0000x reference)
//
#include <hip/hip_runtime.h>

#define Bb 128
#define Ww 128
#define Nn 512
#define ALPHA 0.2f

typedef __attribute__((ext_vector_type(8))) short short8;
typedef __attribute__((ext_vector_type(4))) float f32x4;

__device__ __forceinline__ unsigned f2bf_u(float f) {
  union { float f; unsigned u; } v; v.f = f;
  return (v.u + 0x7fffu + ((v.u >> 16) & 1u)) >> 16;  // RNE f32->bf16 (finite inputs)
}

// ---------------- prep: c[w] = sum_v a2[v] * W_fc[v,w];  c[128] = dot(b_fc, a2) ----------------
__global__ void prep_kernel(const float* __restrict__ Wfc, const float* __restrict__ bfc,
                            const float* __restrict__ attn, float* __restrict__ cvec) {
  const int w = threadIdx.x;  // 0..127
  float a0 = 0.f, a1 = 0.f, a2 = 0.f, a3 = 0.f;
#pragma unroll 4
  for (int v = 0; v < Ww; v += 4) {
    a0 = fmaf(attn[Ww + v + 0], Wfc[(v + 0) * Ww + w], a0);
    a1 = fmaf(attn[Ww + v + 1], Wfc[(v + 1) * Ww + w], a1);
    a2 = fmaf(attn[Ww + v + 2], Wfc[(v + 2) * Ww + w], a2);
    a3 = fmaf(attn[Ww + v + 3], Wfc[(v + 3) * Ww + w], a3);
  }
  cvec[w] = (a0 + a1) + (a2 + a3);
  __shared__ float red[Ww];
  red[w] = bfc[w] * attn[Ww + w];
  __syncthreads();
  if (w == 0) {
    float s = 0.f;
    for (int i = 0; i < Ww; ++i) s += red[i];
    cvec[Ww] = s;
  }
}

// ---------------- kernel A: stream x once, emit s1/s2/s2max-per-slab ----------------
__launch_bounds__(256, 4)
__global__ void stream_s12(const float* __restrict__ x, const float* __restrict__ attn,
                           const float* __restrict__ cvec, float* __restrict__ s1g,
                           float* __restrict__ s2g, float* __restrict__ s2m_g) {
  const int bid = blockIdx.x;       // 512 blocks: (b, 128-n slab)
  const int b = bid >> 2, nc = bid & 3, n0 = nc * 128;
  const int t = threadIdx.x;
  const float* xb = x + (size_t)b * (Ww * Nn);

  __shared__ float sred[8][32][8];
  __shared__ float rmax[4];

  const int w0 = t >> 5;   // 0..7
  const int q  = t & 31;   // float4-col index
  float s1p[4] = {0.f, 0.f, 0.f, 0.f};
  float s2p[4] = {0.f, 0.f, 0.f, 0.f};
#pragma unroll
  for (int k = 0; k < 16; ++k) {
    const int w = w0 + 8 * k;
    const float4 xv = *reinterpret_cast<const float4*>(xb + w * Nn + n0 + 4 * q);
    const float aw = attn[w];
    const float cw = cvec[w];
    s1p[0] = fmaf(xv.x, aw, s1p[0]); s1p[1] = fmaf(xv.y, aw, s1p[1]);
    s1p[2] = fmaf(xv.z, aw, s1p[2]); s1p[3] = fmaf(xv.w, aw, s1p[3]);
    s2p[0] = fmaf(xv.x, cw, s2p[0]); s2p[1] = fmaf(xv.y, cw, s2p[1]);
    s2p[2] = fmaf(xv.z, cw, s2p[2]); s2p[3] = fmaf(xv.w, cw, s2p[3]);
  }
  *reinterpret_cast<float4*>(&sred[w0][q][0]) = make_float4(s1p[0], s1p[1], s1p[2], s1p[3]);
  *reinterpret_cast<float4*>(&sred[w0][q][4]) = make_float4(s2p[0], s2p[1], s2p[2], s2p[3]);
  __syncthreads();

  float s2v = -3.4e38f;
  if (t < 128) {
    const int qq = t >> 2, c = t & 3;
    float a = 0.f, d = 0.f;
#pragma unroll
    for (int g = 0; g < 8; ++g) { a += sred[g][qq][c]; d += sred[g][qq][4 + c]; }
    s1g[b * Nn + n0 + t] = a;
    s2v = d + cvec[Ww];
    s2g[b * Nn + n0 + t] = s2v;
  }
  float m = s2v;
#pragma unroll
  for (int off = 1; off < 64; off <<= 1) m = fmaxf(m, __shfl_xor(m, off));
  if ((t & 63) == 0) rmax[t >> 6] = m;
  __syncthreads();
  if (t == 0) s2m_g[bid] = fmaxf(fmaxf(rmax[0], rmax[1]), fmaxf(rmax[2], rmax[3]));
}

// ---------------- kernel B: double-buffered chunked MFMA attention ----------------
// 256 blocks = (batch b, i-half); pair shares XCD L2 (bid%8). 512 thr, 2 blocks/CU.
__launch_bounds__(512, 4)
__global__ void attn_b(const float* __restrict__ x, const float* __restrict__ s1g,
                       const float* __restrict__ s2g, const float* __restrict__ s2m_g,
                       float* __restrict__ out) {
  __shared__ ushort tile[2][8][129][8];   // 33 KB double buffer
  __shared__ float  s2s[Nn];
  __shared__ float  lred[8][32];

  const int bid = blockIdx.x;
  const int xcd = bid & 7, idx = bid >> 3;
  const int b  = xcd * 16 + (idx >> 1);
  const int i0 = (idx & 1) * 256;
  const int t  = threadIdx.x;
  const int wv = t >> 6, lane = t & 63;
  const int wl = lane & 15, lg = lane >> 4;
  const float* xb = x + (size_t)b * (Ww * Nn);

  s2s[t] = s2g[b * Nn + t];
  const float s2m = fmaxf(fmaxf(s2m_g[4 * b], s2m_g[4 * b + 1]),
                          fmaxf(s2m_g[4 * b + 2], s2m_g[4 * b + 3]));
  float s1i[2], mi[2];
#pragma unroll
  for (int a = 0; a < 2; ++a) {
    s1i[a] = s1g[b * Nn + i0 + wv * 32 + 16 * a + wl];
    const float tt = s1i[a] + s2m;
    mi[a] = fmaxf(tt, ALPHA * tt);  // lrelu monotone -> row max
  }

  const int wrow = t & 127, jgs = t >> 7;     // staging: row wrow, j-groups jgs & jgs+4
  const float* srow = xb + wrow * Nn + jgs * 8;

  // stage chunk 0
  {
    const float4 l0 = *reinterpret_cast<const float4*>(srow + 0);
    const float4 l1 = *reinterpret_cast<const float4*>(srow + 4);
    const float4 h0 = *reinterpret_cast<const float4*>(srow + 32);
    const float4 h1 = *reinterpret_cast<const float4*>(srow + 36);
    uint4 pa, pb;
    pa.x = f2bf_u(l0.x) | (f2bf_u(l0.y) << 16); pa.y = f2bf_u(l0.z) | (f2bf_u(l0.w) << 16);
    pa.z = f2bf_u(l1.x) | (f2bf_u(l1.y) << 16); pa.w = f2bf_u(l1.z) | (f2bf_u(l1.w) << 16);
    pb.x = f2bf_u(h0.x) | (f2bf_u(h0.y) << 16); pb.y = f2bf_u(h0.z) | (f2bf_u(h0.w) << 16);
    pb.z = f2bf_u(h1.x) | (f2bf_u(h1.y) << 16); pb.w = f2bf_u(h1.z) | (f2bf_u(h1.w) << 16);
    *reinterpret_cast<uint4*>(&tile[0][jgs][wrow][0])     = pa;
    *reinterpret_cast<uint4*>(&tile[0][jgs + 4][wrow][0]) = pb;
  }
  __syncthreads();

  f32x4 acc[2][8];
#pragma unroll
  for (int a = 0; a < 2; ++a)
#pragma unroll
    for (int f = 0; f < 8; ++f) acc[a][f] = (f32x4){0.f, 0.f, 0.f, 0.f};
  float lsum0 = 0.f, lsum1 = 0.f;

  for (int c = 0; c < 8; ++c) {
    const int buf = c & 1;
    float4 l0, l1, h0, h1;
    if (c < 7) {  // issue next chunk's loads early (hide under compute)
      const float* s = srow + (c + 1) * 64;
      l0 = *reinterpret_cast<const float4*>(s + 0);
      l1 = *reinterpret_cast<const float4*>(s + 4);
      h0 = *reinterpret_cast<const float4*>(s + 32);
      h1 = *reinterpret_cast<const float4*>(s + 36);
    }

#pragma unroll
    for (int jj = 0; jj < 2; ++jj) {
      const int jb = c * 64 + jj * 32 + 8 * lg;  // this lane's 8 consecutive j's
      float sv[8];
      *reinterpret_cast<float4*>(&sv[0]) = *reinterpret_cast<const float4*>(&s2s[jb]);
      *reinterpret_cast<float4*>(&sv[4]) = *reinterpret_cast<const float4*>(&s2s[jb + 4]);
      short8 af0, af1;
#pragma unroll
      for (int e = 0; e < 8; ++e) {
        const float t0 = s1i[0] + sv[e];
        const float p0 = __expf(fmaxf(t0, ALPHA * t0) - mi[0]);
        lsum0 += p0;
        af0[e] = (short)f2bf_u(p0);
        const float t1 = s1i[1] + sv[e];
        const float p1 = __expf(fmaxf(t1, ALPHA * t1) - mi[1]);
        lsum1 += p1;
        af1[e] = (short)f2bf_u(p1);
      }
#pragma unroll
      for (int f = 0; f < 8; ++f) {
        const short8 bfr = *reinterpret_cast<const short8*>(&tile[buf][jj * 4 + lg][16 * f + wl][0]);
        acc[0][f] = __builtin_amdgcn_mfma_f32_16x16x32_bf16(af0, bfr, acc[0][f], 0, 0, 0);
        acc[1][f] = __builtin_amdgcn_mfma_f32_16x16x32_bf16(af1, bfr, acc[1][f], 0, 0, 0);
      }
    }

    if (c < 7) {  // write-late into the other buffer
      uint4 pa, pb;
      pa.x = f2bf_u(l0.x) | (f2bf_u(l0.y) << 16); pa.y = f2bf_u(l0.z) | (f2bf_u(l0.w) << 16);
      pa.z = f2bf_u(l1.x) | (f2bf_u(l1.y) << 16); pa.w = f2bf_u(l1.z) | (f2bf_u(l1.w) << 16);
      pb.x = f2bf_u(h0.x) | (f2bf_u(h0.y) << 16); pb.y = f2bf_u(h0.z) | (f2bf_u(h0.w) << 16);
      pb.z = f2bf_u(h1.x) | (f2bf_u(h1.y) << 16); pb.w = f2bf_u(h1.z) | (f2bf_u(h1.w) << 16);
      *reinterpret_cast<uint4*>(&tile[buf ^ 1][jgs][wrow][0])     = pa;
      *reinterpret_cast<uint4*>(&tile[buf ^ 1][jgs + 4][wrow][0]) = pb;
    }
    __syncthreads();
  }

  lsum0 += __shfl_xor(lsum0, 16); lsum0 += __shfl_xor(lsum0, 32);
  lsum1 += __shfl_xor(lsum1, 16); lsum1 += __shfl_xor(lsum1, 32);
  if (lg == 0) { lred[wv][wl] = lsum0; lred[wv][16 + wl] = lsum1; }
  __syncthreads();

  float* outb = out + (size_t)b * (Ww * Nn);
#pragma unroll
  for (int a = 0; a < 2; ++a) {
    float invl[4];
#pragma unroll
    for (int qq = 0; qq < 4; ++qq) invl[qq] = 1.0f / lred[wv][16 * a + lg * 4 + qq];
    const int ibase = i0 + wv * 32 + 16 * a + lg * 4;
#pragma unroll
    for (int f = 0; f < 8; ++f) {
      float4 o;
      o.x = 1.f / (1.f + __expf(-(acc[a][f][0] * invl[0])));
      o.y = 1.f / (1.f + __expf(-(acc[a][f][1] * invl[1])));
      o.z = 1.f / (1.f + __expf(-(acc[a][f][2] * invl[2])));
      o.w = 1.f / (1.f + __expf(-(acc[a][f][3] * invl[3])));
      *reinterpret_cast<float4*>(outb + (16 * f + wl) * Nn + ibase) = o;
    }
  }
}

// ---------------- fallback: round-3 fused single kernel (proven, 33.9 us) ----------------
#define TILE_OFF   0
#define TILE_BYTES (64 * 129 * 8 * 2)
#define SRED_OFF   (TILE_OFF + TILE_BYTES)
#define S1S_OFF    (SRED_OFF + 16384)
#define S2S_OFF    (S1S_OFF + 2048)
#define CVS_OFF    (S2S_OFF + 2048)
#define A1S_OFF    (CVS_OFF + 528)
#define LRED_OFF   (A1S_OFF + 512)
#define RMAX_OFF   (LRED_OFF + 1024)
#define SMEM_BYTES (RMAX_OFF + 32)

__launch_bounds__(512, 2)
__global__ void attn_fused(const float* __restrict__ x, const float* __restrict__ Wfc,
                           const float* __restrict__ bfc, const float* __restrict__ attn,
                           float* __restrict__ out) {
  extern __shared__ char smem[];
  ushort* tile = (ushort*)(smem + TILE_OFF);
  float*  sred = (float*)(smem + SRED_OFF);
  float*  s1s  = (float*)(smem + S1S_OFF);
  float*  s2s  = (float*)(smem + S2S_OFF);
  float*  cvs  = (float*)(smem + CVS_OFF);
  float*  a1s  = (float*)(smem + A1S_OFF);
  float*  lred = (float*)(smem + LRED_OFF);
  float*  rmax = (float*)(smem + RMAX_OFF);

  const int bid = blockIdx.x;
  const int xcd = bid & 7, idx = bid >> 3;
  const int b  = xcd * 16 + (idx >> 1);
  const int i0 = (idx & 1) * 256;
  const int t  = threadIdx.x;
  const int wv = t >> 6, lane = t & 63;
  const int wl = lane & 15, lg = lane >> 4;
  const float* xb = x + (size_t)b * (Ww * Nn);

  {
    const int wcol = t & 127, vq = t >> 7;
    float p = 0.f;
#pragma unroll 8
    for (int vi = 0; vi < 32; ++vi) {
      const int v = vq * 32 + vi;
      p = fmaf(attn[Ww + v], Wfc[v * Ww + wcol], p);
    }
    sred[t] = p;
    if (t < Ww) a1s[t] = attn[t];
    if (t < 64) {
      float c0p = fmaf(bfc[t], attn[Ww + t], bfc[t + 64] * attn[Ww + 64 + t]);
#pragma unroll
      for (int off = 32; off; off >>= 1) c0p += __shfl_xor(c0p, off);
      if (t == 0) cvs[Ww] = c0p;
    }
  }
  __syncthreads();
  if (t < Ww) cvs[t] = sred[t] + sred[t + 128] + sred[t + 256] + sred[t + 384];
  __syncthreads();

  const int q = t & 63;
  float s1p[8] = {0, 0, 0, 0, 0, 0, 0, 0};
  float s2p[8] = {0, 0, 0, 0, 0, 0, 0, 0};
#pragma unroll
  for (int k = 0; k < 16; ++k) {
    const int w = wv + 8 * k;
    const float aw = a1s[w];
    const float cw = cvs[w];
    const float4 lo = *reinterpret_cast<const float4*>(xb + w * Nn + 8 * q);
    const float4 hi = *reinterpret_cast<const float4*>(xb + w * Nn + 8 * q + 4);
    s1p[0] = fmaf(lo.x, aw, s1p[0]); s1p[1] = fmaf(lo.y, aw, s1p[1]);
    s1p[2] = fmaf(lo.z, aw, s1p[2]); s1p[3] = fmaf(lo.w, aw, s1p[3]);
    s1p[4] = fmaf(hi.x, aw, s1p[4]); s1p[5] = fmaf(hi.y, aw, s1p[5]);
    s1p[6] = fmaf(hi.z, aw, s1p[6]); s1p[7] = fmaf(hi.w, aw, s1p[7]);
    s2p[0] = fmaf(lo.x, cw, s2p[0]); s2p[1] = fmaf(lo.y, cw, s2p[1]);
    s2p[2] = fmaf(lo.z, cw, s2p[2]); s2p[3] = fmaf(lo.w, cw, s2p[3]);
    s2p[4] = fmaf(hi.x, cw, s2p[4]); s2p[5] = fmaf(hi.y, cw, s2p[5]);
    s2p[6] = fmaf(hi.z, cw, s2p[6]); s2p[7] = fmaf(hi.w, cw, s2p[7]);
    uint4 pk;
    pk.x = f2bf_u(lo.x) | (f2bf_u(lo.y) << 16);
    pk.y = f2bf_u(lo.z) | (f2bf_u(lo.w) << 16);
    pk.z = f2bf_u(hi.x) | (f2bf_u(hi.y) << 16);
    pk.w = f2bf_u(hi.z) | (f2bf_u(hi.w) << 16);
    *reinterpret_cast<uint4*>(tile + ((size_t)q * 129 + w) * 8) = pk;
  }

  {
    f32x4* sv = reinterpret_cast<f32x4*>(&sred[t * 8]);
    sv[0] = (f32x4){s1p[0], s1p[1], s1p[2], s1p[3]};
    sv[1] = (f32x4){s1p[4], s1p[5], s1p[6], s1p[7]};
  }
  __syncthreads();
  {
    const int qq = t >> 3, ee = t & 7;
    float a = 0.f;
#pragma unroll
    for (int g = 0; g < 8; ++g) a += sred[((g * 64) + qq) * 8 + ee];
    s1s[t] = a;
  }
  __syncthreads();
  {
    f32x4* sv = reinterpret_cast<f32x4*>(&sred[t * 8]);
    sv[0] = (f32x4){s2p[0], s2p[1], s2p[2], s2p[3]};
    sv[1] = (f32x4){s2p[4], s2p[5], s2p[6], s2p[7]};
  }
  __syncthreads();
  {
    const int qq = t >> 3, ee = t & 7;
    float d = 0.f;
#pragma unroll
    for (int g = 0; g < 8; ++g) d += sred[((g * 64) + qq) * 8 + ee];
    s2s[t] = d + cvs[Ww];
  }

  {
    float m = s2s[t];
#pragma unroll
    for (int off = 1; off < 64; off <<= 1) m = fmaxf(m, __shfl_xor(m, off));
    if (lane == 0) rmax[wv] = m;
  }
  __syncthreads();
  float s2m = rmax[0];
#pragma unroll
  for (int g = 1; g < 8; ++g) s2m = fmaxf(s2m, rmax[g]);

  float s1i[2], mi[2];
#pragma unroll
  for (int a = 0; a < 2; ++a) {
    const float s1v = s1s[i0 + wv * 32 + 16 * a + wl];
    s1i[a] = s1v;
    const float tt = s1v + s2m;
    mi[a] = fmaxf(tt, ALPHA * tt);
  }

  f32x4 acc[2][8];
#pragma unroll
  for (int a = 0; a < 2; ++a)
#pragma unroll
    for (int f = 0; f < 8; ++f) acc[a][f] = (f32x4){0.f, 0.f, 0.f, 0.f};
  float lsum0 = 0.f, lsum1 = 0.f;

  for (int jj = 0; jj < 16; ++jj) {
    const int jb = jj * 32 + 8 * lg;
    float sv[8];
    *reinterpret_cast<float4*>(&sv[0]) = *reinterpret_cast<const float4*>(&s2s[jb]);
    *reinterpret_cast<float4*>(&sv[4]) = *reinterpret_cast<const float4*>(&s2s[jb + 4]);
    short8 af0, af1;
#pragma unroll
    for (int e = 0; e < 8; ++e) {
      const float t0 = s1i[0] + sv[e];
      const float p0 = __expf(fmaxf(t0, ALPHA * t0) - mi[0]);
      lsum0 += p0;
      af0[e] = (short)f2bf_u(p0);
      const float t1 = s1i[1] + sv[e];
      const float p1 = __expf(fmaxf(t1, ALPHA * t1) - mi[1]);
      lsum1 += p1;
      af1[e] = (short)f2bf_u(p1);
    }
    const int jg = jj * 4 + lg;
#pragma unroll
    for (int f = 0; f < 8; ++f) {
      const short8 bfr = *reinterpret_cast<const short8*>(tile + ((size_t)jg * 129 + 16 * f + wl) * 8);
      acc[0][f] = __builtin_amdgcn_mfma_f32_16x16x32_bf16(af0, bfr, acc[0][f], 0, 0, 0);
      acc[1][f] = __builtin_amdgcn_mfma_f32_16x16x32_bf16(af1, bfr, acc[1][f], 0, 0, 0);
    }
  }

  lsum0 += __shfl_xor(lsum0, 16); lsum0 += __shfl_xor(lsum0, 32);
  lsum1 += __shfl_xor(lsum1, 16); lsum1 += __shfl_xor(lsum1, 32);
  if (lg == 0) { lred[wv * 32 + wl] = lsum0; lred[wv * 32 + 16 + wl] = lsum1; }
  __syncthreads();

  float* outb = out + (size_t)b * (Ww * Nn);
#pragma unroll
  for (int a = 0; a < 2; ++a) {
    float invl[4];
#pragma unroll
    for (int qq = 0; qq < 4; ++qq) invl[qq] = 1.0f / lred[wv * 32 + 16 * a + lg * 4 + qq];
    const int ibase = i0 + wv * 32 + 16 * a + lg * 4;
#pragma unroll
    for (int f = 0; f < 8; ++f) {
      float4 o;
      o.x = 1.f / (1.f + __expf(-(acc[a][f][0] * invl[0])));
      o.y = 1.f / (1.f + __expf(-(acc[a][f][1] * invl[1])));
      o.z = 1.f / (1.f + __expf(-(acc[a][f][2] * invl[2])));
      o.w = 1.f / (1.f + __expf(-(acc[a][f][3] * invl[3])));
      *reinterpret_cast<float4*>(outb + (16 * f + wl) * Nn + ibase) = o;
    }
  }
}

extern "C" void kernel_launch(void* const* d_in, const int* in_sizes, int n_in,
                              void* d_out, int out_size, void* d_ws, size_t ws_size,
                              hipStream_t stream) {
  const float* x    = (const float*)d_in[0];  // (128,128,512)
  const float* Wfc  = (const float*)d_in[1];  // (128,128)
  const float* bfc  = (const float*)d_in[2];  // (128,)
  const float* attn = (const float*)d_in[3];  // (256,1)
  float* out = (float*)d_out;                 // (128,128,512)

  char* ws = (char*)d_ws;
  float* cvec  = (float*)ws;                       // 1 KB slot
  float* s1g   = (float*)(ws + 1024);              // 256 KB
  float* s2g   = (float*)(ws + 1024 + 262144);     // 256 KB
  float* s2m_g = (float*)(ws + 1024 + 2 * 262144); // 2 KB
  const size_t NEED = 1024 + 2 * 262144 + 2048;

  if (ws_size >= NEED) {
    prep_kernel<<<1, 128, 0, stream>>>(Wfc, bfc, attn, cvec);
    stream_s12<<<512, 256, 0, stream>>>(x, attn, cvec, s1g, s2g, s2m_g);
    attn_b<<<256, 512, 0, stream>>>(x, s1g, s2g, s2m_g, out);
  } else {
    hipError_t e = hipFuncSetAttribute(reinterpret_cast<const void*>(&attn_fused),
                                       hipFuncAttributeMaxDynamicSharedMemorySize,
                                       SMEM_BYTES);
    (void)e;
    attn_fused<<<256, 512, SMEM_BYTES, stream>>>(x, Wfc, bfc, attn, out);
  }
}

// Round 5
// 45.516 us; speedup vs baseline: 1.4786x; 1.4786x over previous
//
#include <hip/hip_runtime.h>

#define Bb 128
#define Ww 128
#define Nn 512
#define ALPHA 0.2f

typedef __attribute__((ext_vector_type(8))) short short8;
typedef __attribute__((ext_vector_type(4))) float f32x4;

__device__ __forceinline__ unsigned f2bf_u(float f) {
  union { float f; unsigned u; } v; v.f = f;
  return (v.u + 0x7fffu + ((v.u >> 16) & 1u)) >> 16;  // RNE f32->bf16
}

// v_cvt_pk_bf16_f32: packs (lo,hi) -> u32 of 2 bf16, RNE (same as f2bf_u)
__device__ __forceinline__ unsigned pk_bf16(float lo, float hi) {
  unsigned r;
  asm("v_cvt_pk_bf16_f32 %0, %1, %2" : "=v"(r) : "v"(lo), "v"(hi));
  return r;
}

// ---------------- kernel A: cvec (folded) + stream x once -> s1/s2/s2max ----------------
__launch_bounds__(256, 4)
__global__ void stream_s12(const float* __restrict__ x, const float* __restrict__ Wfc,
                           const float* __restrict__ bfc, const float* __restrict__ attn,
                           float* __restrict__ s1g, float* __restrict__ s2g,
                           float* __restrict__ s2m_g) {
  const int bid = blockIdx.x;       // 512 blocks: (b, 128-n slab)
  const int b = bid >> 2, nc = bid & 3, n0 = nc * 128;
  const int t = threadIdx.x;
  const float* xb = x + (size_t)b * (Ww * Nn);

  __shared__ float sred[8][32][8];
  __shared__ float rmax[4];
  __shared__ float cvs[Ww + 1];
  __shared__ float a1s[Ww];
  __shared__ float cred[256];

  // cvec[w] = sum_v a2[v]*Wfc[v][w]  (each block redundantly; Wfc is L2-hot)
  {
    const int w = t & 127, h = t >> 7;  // two v-halves
    float p = 0.f;
#pragma unroll 8
    for (int vi = 0; vi < 64; ++vi) {
      const int v = h * 64 + vi;
      p = fmaf(attn[Ww + v], Wfc[v * Ww + w], p);
    }
    cred[t] = p;
    if (t < Ww) a1s[t] = attn[t];
    if (t < 64) {  // c0 = dot(b_fc, a2)
      float c0p = fmaf(bfc[t], attn[Ww + t], bfc[t + 64] * attn[Ww + 64 + t]);
#pragma unroll
      for (int off = 32; off; off >>= 1) c0p += __shfl_xor(c0p, off);
      if (t == 0) cvs[Ww] = c0p;
    }
  }
  __syncthreads();
  if (t < Ww) cvs[t] = cred[t] + cred[t + 128];
  __syncthreads();

  const int w0 = t >> 5;   // 0..7
  const int q  = t & 31;   // float4-col index
  float s1p[4] = {0.f, 0.f, 0.f, 0.f};
  float s2p[4] = {0.f, 0.f, 0.f, 0.f};
#pragma unroll
  for (int k = 0; k < 16; ++k) {
    const int w = w0 + 8 * k;
    const float4 xv = *reinterpret_cast<const float4*>(xb + w * Nn + n0 + 4 * q);
    const float aw = a1s[w];
    const float cw = cvs[w];
    s1p[0] = fmaf(xv.x, aw, s1p[0]); s1p[1] = fmaf(xv.y, aw, s1p[1]);
    s1p[2] = fmaf(xv.z, aw, s1p[2]); s1p[3] = fmaf(xv.w, aw, s1p[3]);
    s2p[0] = fmaf(xv.x, cw, s2p[0]); s2p[1] = fmaf(xv.y, cw, s2p[1]);
    s2p[2] = fmaf(xv.z, cw, s2p[2]); s2p[3] = fmaf(xv.w, cw, s2p[3]);
  }
  *reinterpret_cast<float4*>(&sred[w0][q][0]) = make_float4(s1p[0], s1p[1], s1p[2], s1p[3]);
  *reinterpret_cast<float4*>(&sred[w0][q][4]) = make_float4(s2p[0], s2p[1], s2p[2], s2p[3]);
  __syncthreads();

  float s2v = -3.4e38f;
  if (t < 128) {
    const int qq = t >> 2, c = t & 3;
    float a = 0.f, d = 0.f;
#pragma unroll
    for (int g = 0; g < 8; ++g) { a += sred[g][qq][c]; d += sred[g][qq][4 + c]; }
    s1g[b * Nn + n0 + t] = a;
    s2v = d + cvs[Ww];
    s2g[b * Nn + n0 + t] = s2v;
  }
  float m = s2v;
#pragma unroll
  for (int off = 1; off < 64; off <<= 1) m = fmaxf(m, __shfl_xor(m, off));
  if ((t & 63) == 0) rmax[t >> 6] = m;
  __syncthreads();
  if (t == 0) s2m_g[bid] = fmaxf(fmaxf(rmax[0], rmax[1]), fmaxf(rmax[2], rmax[3]));
}

// ---------------- kernel B: MFMA attention, round-1 proven shape + dbuf pipeline ----------------
// 512 blocks = (batch b, i-quarter). XCD-grouped: blocks of one batch share an XCD L2.
__launch_bounds__(256, 2)
__global__ void attn_c(const float* __restrict__ x, const float* __restrict__ s1g,
                       const float* __restrict__ s2g, const float* __restrict__ s2m_g,
                       float* __restrict__ out) {
  __shared__ ushort tile[2][8][128][8];   // 32 KB double buffer (0-conflict layout)
  __shared__ float  s2s[Nn];
  __shared__ float  lred[4][32];

  const int bid = blockIdx.x;            // 0..511
  const int xcd = bid & 7, idx = bid >> 3;
  const int b  = xcd * 16 + (idx >> 2);
  const int i0 = (idx & 3) * 128;
  const int t  = threadIdx.x;
  const int wv = t >> 6, lane = t & 63;
  const int wl = lane & 15, lg = lane >> 4;
  const float* xb = x + (size_t)b * (Ww * Nn);

  s2s[t] = s2g[b * Nn + t];
  s2s[256 + t] = s2g[b * Nn + 256 + t];
  const float s2m = fmaxf(fmaxf(s2m_g[4 * b], s2m_g[4 * b + 1]),
                          fmaxf(s2m_g[4 * b + 2], s2m_g[4 * b + 3]));
  float s1i[2], mi[2];
#pragma unroll
  for (int a = 0; a < 2; ++a) {
    s1i[a] = s1g[b * Nn + i0 + wv * 32 + 16 * a + wl];
    const float tt = s1i[a] + s2m;
    mi[a] = fmaxf(tt, ALPHA * tt);  // lrelu monotone -> row max
  }

  // staging geometry: w = t&127 fixed; jg = (t>>7) + 2k, k=0..3
  const int wrow = t & 127;
  const int jg0  = t >> 7;           // 0 or 1
  const float* srow = xb + wrow * Nn;

  // stage chunk 0 into buf 0
  {
#pragma unroll
    for (int k = 0; k < 4; ++k) {
      const int jg = jg0 + 2 * k;
      const float4 lo = *reinterpret_cast<const float4*>(srow + jg * 8);
      const float4 hi = *reinterpret_cast<const float4*>(srow + jg * 8 + 4);
      uint4 pk;
      pk.x = pk_bf16(lo.x, lo.y); pk.y = pk_bf16(lo.z, lo.w);
      pk.z = pk_bf16(hi.x, hi.y); pk.w = pk_bf16(hi.z, hi.w);
      *reinterpret_cast<uint4*>(&tile[0][jg][wrow][0]) = pk;
    }
  }
  __syncthreads();

  f32x4 acc[2][8];
#pragma unroll
  for (int a = 0; a < 2; ++a)
#pragma unroll
    for (int f = 0; f < 8; ++f) acc[a][f] = (f32x4){0.f, 0.f, 0.f, 0.f};
  float lsum0 = 0.f, lsum1 = 0.f;

  for (int c = 0; c < 8; ++c) {
    const int buf = c & 1;
    float4 raw[8];
    if (c < 7) {  // issue next chunk's 8 float4 loads; first use is after compute,
                  // so the vmcnt wait lands after the MFMA/exp section
      const float* s = srow + (c + 1) * 64;
#pragma unroll
      for (int k = 0; k < 4; ++k) {
        const int jg = jg0 + 2 * k;
        raw[2 * k]     = *reinterpret_cast<const float4*>(s + jg * 8);
        raw[2 * k + 1] = *reinterpret_cast<const float4*>(s + jg * 8 + 4);
      }
    }

#pragma unroll
    for (int jj = 0; jj < 2; ++jj) {
      const int jb = c * 64 + jj * 32 + 8 * lg;  // this lane's 8 consecutive j's
      float sv[8];
      *reinterpret_cast<float4*>(&sv[0]) = *reinterpret_cast<const float4*>(&s2s[jb]);
      *reinterpret_cast<float4*>(&sv[4]) = *reinterpret_cast<const float4*>(&s2s[jb + 4]);
      short8 af0, af1;
#pragma unroll
      for (int e = 0; e < 8; ++e) {
        const float t0 = s1i[0] + sv[e];
        const float p0 = __expf(fmaxf(t0, ALPHA * t0) - mi[0]);
        lsum0 += p0;
        af0[e] = (short)f2bf_u(p0);
        const float t1 = s1i[1] + sv[e];
        const float p1 = __expf(fmaxf(t1, ALPHA * t1) - mi[1]);
        lsum1 += p1;
        af1[e] = (short)f2bf_u(p1);
      }
#pragma unroll
      for (int f = 0; f < 8; ++f) {
        const short8 bfr = *reinterpret_cast<const short8*>(&tile[buf][jj * 4 + lg][16 * f + wl][0]);
        acc[0][f] = __builtin_amdgcn_mfma_f32_16x16x32_bf16(af0, bfr, acc[0][f], 0, 0, 0);
        acc[1][f] = __builtin_amdgcn_mfma_f32_16x16x32_bf16(af1, bfr, acc[1][f], 0, 0, 0);
      }
    }

    if (c < 7) {  // pack + write-late into the other buffer
#pragma unroll
      for (int k = 0; k < 4; ++k) {
        const int jg = jg0 + 2 * k;
        uint4 pk;
        pk.x = pk_bf16(raw[2 * k].x, raw[2 * k].y);
        pk.y = pk_bf16(raw[2 * k].z, raw[2 * k].w);
        pk.z = pk_bf16(raw[2 * k + 1].x, raw[2 * k + 1].y);
        pk.w = pk_bf16(raw[2 * k + 1].z, raw[2 * k + 1].w);
        *reinterpret_cast<uint4*>(&tile[buf ^ 1][jg][wrow][0]) = pk;
      }
    }
    __syncthreads();
  }

  lsum0 += __shfl_xor(lsum0, 16); lsum0 += __shfl_xor(lsum0, 32);
  lsum1 += __shfl_xor(lsum1, 16); lsum1 += __shfl_xor(lsum1, 32);
  if (lg == 0) { lred[wv][wl] = lsum0; lred[wv][16 + wl] = lsum1; }
  __syncthreads();

  float* outb = out + (size_t)b * (Ww * Nn);
#pragma unroll
  for (int a = 0; a < 2; ++a) {
    float invl[4];
#pragma unroll
    for (int qq = 0; qq < 4; ++qq) invl[qq] = 1.0f / lred[wv][16 * a + lg * 4 + qq];
    const int ibase = i0 + wv * 32 + 16 * a + lg * 4;
#pragma unroll
    for (int f = 0; f < 8; ++f) {
      float4 o;
      o.x = 1.f / (1.f + __expf(-(acc[a][f][0] * invl[0])));
      o.y = 1.f / (1.f + __expf(-(acc[a][f][1] * invl[1])));
      o.z = 1.f / (1.f + __expf(-(acc[a][f][2] * invl[2])));
      o.w = 1.f / (1.f + __expf(-(acc[a][f][3] * invl[3])));
      *reinterpret_cast<float4*>(outb + (16 * f + wl) * Nn + ibase) = o;
    }
  }
}

// ---------------- fallback: round-3 fused single kernel (proven, 33.9 us) ----------------
#define TILE_OFF   0
#define TILE_BYTES (64 * 129 * 8 * 2)
#define SRED_OFF   (TILE_OFF + TILE_BYTES)
#define S1S_OFF    (SRED_OFF + 16384)
#define S2S_OFF    (S1S_OFF + 2048)
#define CVS_OFF    (S2S_OFF + 2048)
#define A1S_OFF    (CVS_OFF + 528)
#define LRED_OFF   (A1S_OFF + 512)
#define RMAX_OFF   (LRED_OFF + 1024)
#define SMEM_BYTES (RMAX_OFF + 32)

__launch_bounds__(512, 2)
__global__ void attn_fused(const float* __restrict__ x, const float* __restrict__ Wfc,
                           const float* __restrict__ bfc, const float* __restrict__ attn,
                           float* __restrict__ out) {
  extern __shared__ char smem[];
  ushort* tile = (ushort*)(smem + TILE_OFF);
  float*  sred = (float*)(smem + SRED_OFF);
  float*  s1s  = (float*)(smem + S1S_OFF);
  float*  s2s  = (float*)(smem + S2S_OFF);
  float*  cvs  = (float*)(smem + CVS_OFF);
  float*  a1s  = (float*)(smem + A1S_OFF);
  float*  lred = (float*)(smem + LRED_OFF);
  float*  rmax = (float*)(smem + RMAX_OFF);

  const int bid = blockIdx.x;
  const int xcd = bid & 7, idx = bid >> 3;
  const int b  = xcd * 16 + (idx >> 1);
  const int i0 = (idx & 1) * 256;
  const int t  = threadIdx.x;
  const int wv = t >> 6, lane = t & 63;
  const int wl = lane & 15, lg = lane >> 4;
  const float* xb = x + (size_t)b * (Ww * Nn);

  {
    const int wcol = t & 127, vq = t >> 7;
    float p = 0.f;
#pragma unroll 8
    for (int vi = 0; vi < 32; ++vi) {
      const int v = vq * 32 + vi;
      p = fmaf(attn[Ww + v], Wfc[v * Ww + wcol], p);
    }
    sred[t] = p;
    if (t < Ww) a1s[t] = attn[t];
    if (t < 64) {
      float c0p = fmaf(bfc[t], attn[Ww + t], bfc[t + 64] * attn[Ww + 64 + t]);
#pragma unroll
      for (int off = 32; off; off >>= 1) c0p += __shfl_xor(c0p, off);
      if (t == 0) cvs[Ww] = c0p;
    }
  }
  __syncthreads();
  if (t < Ww) cvs[t] = sred[t] + sred[t + 128] + sred[t + 256] + sred[t + 384];
  __syncthreads();

  const int q = t & 63;
  float s1p[8] = {0, 0, 0, 0, 0, 0, 0, 0};
  float s2p[8] = {0, 0, 0, 0, 0, 0, 0, 0};
#pragma unroll
  for (int k = 0; k < 16; ++k) {
    const int w = wv + 8 * k;
    const float aw = a1s[w];
    const float cw = cvs[w];
    const float4 lo = *reinterpret_cast<const float4*>(xb + w * Nn + 8 * q);
    const float4 hi = *reinterpret_cast<const float4*>(xb + w * Nn + 8 * q + 4);
    s1p[0] = fmaf(lo.x, aw, s1p[0]); s1p[1] = fmaf(lo.y, aw, s1p[1]);
    s1p[2] = fmaf(lo.z, aw, s1p[2]); s1p[3] = fmaf(lo.w, aw, s1p[3]);
    s1p[4] = fmaf(hi.x, aw, s1p[4]); s1p[5] = fmaf(hi.y, aw, s1p[5]);
    s1p[6] = fmaf(hi.z, aw, s1p[6]); s1p[7] = fmaf(hi.w, aw, s1p[7]);
    s2p[0] = fmaf(lo.x, cw, s2p[0]); s2p[1] = fmaf(lo.y, cw, s2p[1]);
    s2p[2] = fmaf(lo.z, cw, s2p[2]); s2p[3] = fmaf(lo.w, cw, s2p[3]);
    s2p[4] = fmaf(hi.x, cw, s2p[4]); s2p[5] = fmaf(hi.y, cw, s2p[5]);
    s2p[6] = fmaf(hi.z, cw, s2p[6]); s2p[7] = fmaf(hi.w, cw, s2p[7]);
    uint4 pk;
    pk.x = f2bf_u(lo.x) | (f2bf_u(lo.y) << 16);
    pk.y = f2bf_u(lo.z) | (f2bf_u(lo.w) << 16);
    pk.z = f2bf_u(hi.x) | (f2bf_u(hi.y) << 16);
    pk.w = f2bf_u(hi.z) | (f2bf_u(hi.w) << 16);
    *reinterpret_cast<uint4*>(tile + ((size_t)q * 129 + w) * 8) = pk;
  }

  {
    f32x4* sv = reinterpret_cast<f32x4*>(&sred[t * 8]);
    sv[0] = (f32x4){s1p[0], s1p[1], s1p[2], s1p[3]};
    sv[1] = (f32x4){s1p[4], s1p[5], s1p[6], s1p[7]};
  }
  __syncthreads();
  {
    const int qq = t >> 3, ee = t & 7;
    float a = 0.f;
#pragma unroll
    for (int g = 0; g < 8; ++g) a += sred[((g * 64) + qq) * 8 + ee];
    s1s[t] = a;
  }
  __syncthreads();
  {
    f32x4* sv = reinterpret_cast<f32x4*>(&sred[t * 8]);
    sv[0] = (f32x4){s2p[0], s2p[1], s2p[2], s2p[3]};
    sv[1] = (f32x4){s2p[4], s2p[5], s2p[6], s2p[7]};
  }
  __syncthreads();
  {
    const int qq = t >> 3, ee = t & 7;
    float d = 0.f;
#pragma unroll
    for (int g = 0; g < 8; ++g) d += sred[((g * 64) + qq) * 8 + ee];
    s2s[t] = d + cvs[Ww];
  }

  {
    float m = s2s[t];
#pragma unroll
    for (int off = 1; off < 64; off <<= 1) m = fmaxf(m, __shfl_xor(m, off));
    if (lane == 0) rmax[wv] = m;
  }
  __syncthreads();
  float s2m = rmax[0];
#pragma unroll
  for (int g = 1; g < 8; ++g) s2m = fmaxf(s2m, rmax[g]);

  float s1i[2], mi[2];
#pragma unroll
  for (int a = 0; a < 2; ++a) {
    const float s1v = s1s[i0 + wv * 32 + 16 * a + wl];
    s1i[a] = s1v;
    const float tt = s1v + s2m;
    mi[a] = fmaxf(tt, ALPHA * tt);
  }

  f32x4 acc[2][8];
#pragma unroll
  for (int a = 0; a < 2; ++a)
#pragma unroll
    for (int f = 0; f < 8; ++f) acc[a][f] = (f32x4){0.f, 0.f, 0.f, 0.f};
  float lsum0 = 0.f, lsum1 = 0.f;

  for (int jj = 0; jj < 16; ++jj) {
    const int jb = jj * 32 + 8 * lg;
    float sv[8];
    *reinterpret_cast<float4*>(&sv[0]) = *reinterpret_cast<const float4*>(&s2s[jb]);
    *reinterpret_cast<float4*>(&sv[4]) = *reinterpret_cast<const float4*>(&s2s[jb + 4]);
    short8 af0, af1;
#pragma unroll
    for (int e = 0; e < 8; ++e) {
      const float t0 = s1i[0] + sv[e];
      const float p0 = __expf(fmaxf(t0, ALPHA * t0) - mi[0]);
      lsum0 += p0;
      af0[e] = (short)f2bf_u(p0);
      const float t1 = s1i[1] + sv[e];
      const float p1 = __expf(fmaxf(t1, ALPHA * t1) - mi[1]);
      lsum1 += p1;
      af1[e] = (short)f2bf_u(p1);
    }
    const int jg = jj * 4 + lg;
#pragma unroll
    for (int f = 0; f < 8; ++f) {
      const short8 bfr = *reinterpret_cast<const short8*>(tile + ((size_t)jg * 129 + 16 * f + wl) * 8);
      acc[0][f] = __builtin_amdgcn_mfma_f32_16x16x32_bf16(af0, bfr, acc[0][f], 0, 0, 0);
      acc[1][f] = __builtin_amdgcn_mfma_f32_16x16x32_bf16(af1, bfr, acc[1][f], 0, 0, 0);
    }
  }

  lsum0 += __shfl_xor(lsum0, 16); lsum0 += __shfl_xor(lsum0, 32);
  lsum1 += __shfl_xor(lsum1, 16); lsum1 += __shfl_xor(lsum1, 32);
  if (lg == 0) { lred[wv * 32 + wl] = lsum0; lred[wv * 32 + 16 + wl] = lsum1; }
  __syncthreads();

  float* outb = out + (size_t)b * (Ww * Nn);
#pragma unroll
  for (int a = 0; a < 2; ++a) {
    float invl[4];
#pragma unroll
    for (int qq = 0; qq < 4; ++qq) invl[qq] = 1.0f / lred[wv * 32 + 16 * a + lg * 4 + qq];
    const int ibase = i0 + wv * 32 + 16 * a + lg * 4;
#pragma unroll
    for (int f = 0; f < 8; ++f) {
      float4 o;
      o.x = 1.f / (1.f + __expf(-(acc[a][f][0] * invl[0])));
      o.y = 1.f / (1.f + __expf(-(acc[a][f][1] * invl[1])));
      o.z = 1.f / (1.f + __expf(-(acc[a][f][2] * invl[2])));
      o.w = 1.f / (1.f + __expf(-(acc[a][f][3] * invl[3])));
      *reinterpret_cast<float4*>(outb + (16 * f + wl) * Nn + ibase) = o;
    }
  }
}

extern "C" void kernel_launch(void* const* d_in, const int* in_sizes, int n_in,
                              void* d_out, int out_size, void* d_ws, size_t ws_size,
                              hipStream_t stream) {
  const float* x    = (const float*)d_in[0];  // (128,128,512)
  const float* Wfc  = (const float*)d_in[1];  // (128,128)
  const float* bfc  = (const float*)d_in[2];  // (128,)
  const float* attn = (const float*)d_in[3];  // (256,1)
  float* out = (float*)d_out;                 // (128,128,512)

  char* ws = (char*)d_ws;
  float* s1g   = (float*)ws;                       // 256 KB
  float* s2g   = (float*)(ws + 262144);            // 256 KB
  float* s2m_g = (float*)(ws + 2 * 262144);        // 2 KB
  const size_t NEED = 2 * 262144 + 2048;

  if (ws_size >= NEED) {
    stream_s12<<<512, 256, 0, stream>>>(x, Wfc, bfc, attn, s1g, s2g, s2m_g);
    attn_c<<<512, 256, 0, stream>>>(x, s1g, s2g, s2m_g, out);
  } else {
    (void)hipFuncSetAttribute(reinterpret_cast<const void*>(&attn_fused),
                              hipFuncAttributeMaxDynamicSharedMemorySize, SMEM_BYTES);
    attn_fused<<<256, 512, SMEM_BYTES, stream>>>(x, Wfc, bfc, attn, out);
  }
}

// Round 6
// 38.446 us; speedup vs baseline: 1.7506x; 1.1839x over previous
//
#include <hip/hip_runtime.h>

#define Bb 128
#define Ww 128
#define Nn 512
#define ALPHA 0.2f

typedef __attribute__((ext_vector_type(8))) short short8;
typedef __attribute__((ext_vector_type(4))) float f32x4;

__device__ __forceinline__ unsigned f2bf_u(float f) {
  union { float f; unsigned u; } v; v.f = f;
  return (v.u + 0x7fffu + ((v.u >> 16) & 1u)) >> 16;  // RNE f32->bf16
}

// v_cvt_pk_bf16_f32: packs (lo,hi) -> u32 of 2 bf16, RNE (same as f2bf_u)
__device__ __forceinline__ unsigned pk_bf16(float lo, float hi) {
  unsigned r;
  asm("v_cvt_pk_bf16_f32 %0, %1, %2" : "=v"(r) : "v"(lo), "v"(hi));
  return r;
}

__device__ __forceinline__ void gld_lds16(const void* g, void* l) {
  auto gp = reinterpret_cast<const __attribute__((address_space(1))) unsigned int*>(
      reinterpret_cast<uintptr_t>(g));
  auto lp = reinterpret_cast<__attribute__((address_space(3))) unsigned int*>(
      reinterpret_cast<uintptr_t>(l));
  __builtin_amdgcn_global_load_lds(gp, lp, 16, 0, 0);
}

// ---------------- kernel 1: read x f32 ONCE -> s1/s2/s2max + bf16 xbf (staging layout) ----
// 512 blocks = (b, 128-n slab), XCD-grouped identically to attn_d so xbf stays in-XCD L2.
__launch_bounds__(256, 3)
__global__ void stream_pack(const float* __restrict__ x, const float* __restrict__ Wfc,
                            const float* __restrict__ bfc, const float* __restrict__ attn,
                            ushort* __restrict__ xbf, float* __restrict__ s1g,
                            float* __restrict__ s2g, float* __restrict__ s2m_g) {
  const int bid = blockIdx.x;
  const int xcd = bid & 7, idx = bid >> 3;     // idx 0..63
  const int b  = xcd * 16 + (idx >> 2);
  const int nc = idx & 3;
  const int n0 = nc * 128;
  const int t  = threadIdx.x;
  const float* xb = x + (size_t)b * (Ww * Nn);

  __shared__ ushort tile_st[16][129][8];   // 33 KB transpose staging
  __shared__ float  sred[8][32][8];        // 8 KB
  __shared__ float  cvs[Ww + 1];
  __shared__ float  a1s[Ww];
  __shared__ float  cred[256];
  __shared__ float  rmax[4];

  // cvec[w] = sum_v a2[v]*Wfc[v][w] (redundant per block; Wfc L2/L3-hot), c0 = b_fc . a2
  {
    const int w = t & 127, h = t >> 7;
    float p = 0.f;
#pragma unroll 8
    for (int vi = 0; vi < 64; ++vi) {
      const int v = h * 64 + vi;
      p = fmaf(attn[Ww + v], Wfc[v * Ww + w], p);
    }
    cred[t] = p;
    if (t < Ww) a1s[t] = attn[t];
    if (t < 64) {
      float c0p = fmaf(bfc[t], attn[Ww + t], bfc[t + 64] * attn[Ww + 64 + t]);
#pragma unroll
      for (int off = 32; off; off >>= 1) c0p += __shfl_xor(c0p, off);
      if (t == 0) cvs[Ww] = c0p;
    }
  }
  __syncthreads();
  if (t < Ww) cvs[t] = cred[t] + cred[t + 128];
  __syncthreads();

  // stream x once: accumulate s1/s2 partials + write bf16 into transpose staging
  const int w0 = t >> 5;   // 0..7
  const int q  = t & 31;   // float4 col in slab
  float s1p[4] = {0.f, 0.f, 0.f, 0.f};
  float s2p[4] = {0.f, 0.f, 0.f, 0.f};
#pragma unroll
  for (int k = 0; k < 16; ++k) {
    const int w = w0 + 8 * k;
    const float4 xv = *reinterpret_cast<const float4*>(xb + w * Nn + n0 + 4 * q);
    const float aw = a1s[w];
    const float cw = cvs[w];
    s1p[0] = fmaf(xv.x, aw, s1p[0]); s1p[1] = fmaf(xv.y, aw, s1p[1]);
    s1p[2] = fmaf(xv.z, aw, s1p[2]); s1p[3] = fmaf(xv.w, aw, s1p[3]);
    s2p[0] = fmaf(xv.x, cw, s2p[0]); s2p[1] = fmaf(xv.y, cw, s2p[1]);
    s2p[2] = fmaf(xv.z, cw, s2p[2]); s2p[3] = fmaf(xv.w, cw, s2p[3]);
    uint2 pk;
    pk.x = pk_bf16(xv.x, xv.y);
    pk.y = pk_bf16(xv.z, xv.w);
    *reinterpret_cast<uint2*>(&tile_st[q >> 1][w][(q & 1) * 4]) = pk;
  }
  *reinterpret_cast<float4*>(&sred[w0][q][0]) = make_float4(s1p[0], s1p[1], s1p[2], s1p[3]);
  *reinterpret_cast<float4*>(&sred[w0][q][4]) = make_float4(s2p[0], s2p[1], s2p[2], s2p[3]);
  __syncthreads();

  // s1/s2 finalize + per-slab max
  float s2v = -3.4e38f;
  if (t < 128) {
    const int qq = t >> 2, c = t & 3;
    float a = 0.f, d = 0.f;
#pragma unroll
    for (int g = 0; g < 8; ++g) { a += sred[g][qq][c]; d += sred[g][qq][4 + c]; }
    s1g[b * Nn + n0 + t] = a;
    s2v = d + cvs[Ww];
    s2g[b * Nn + n0 + t] = s2v;
  }
  float m = s2v;
#pragma unroll
  for (int off = 1; off < 64; off <<= 1) m = fmaxf(m, __shfl_xor(m, off));
  if ((t & 63) == 0) rmax[t >> 6] = m;

  // write xbf: [b][jg=n>>3][w][n&7], 16B per (jg,w) — attn staging-ready
#pragma unroll
  for (int k = 0; k < 8; ++k) {
    const int u = t + 256 * k;
    const int jg = u >> 7, w = u & 127;
    const uint4 v4 = *reinterpret_cast<const uint4*>(&tile_st[jg][w][0]);
    *reinterpret_cast<uint4*>(xbf + (((size_t)b * 64 + nc * 16 + jg) * 128 + w) * 8) = v4;
  }
  __syncthreads();
  if (t == 0) s2m_g[b * 4 + nc] = fmaxf(fmaxf(rmax[0], rmax[1]), fmaxf(rmax[2], rmax[3]));
}

// ---------------- kernel 2: MFMA attention from bf16 xbf via global_load_lds ----------------
// 1024 blocks = (b, i-eighth). 4 waves x 16 i-rows. 4 blocks/CU. XCD decode matches pack.
__launch_bounds__(256, 4)
__global__ void attn_d(const ushort* __restrict__ xbf, const float* __restrict__ s1g,
                       const float* __restrict__ s2g, const float* __restrict__ s2m_g,
                       float* __restrict__ out) {
  __shared__ ushort tile[2][8][128][8];   // 32 KB double buffer (0-conflict layout)
  __shared__ float  s2s[Nn];
  __shared__ float  lred[4][16];

  const int bid = blockIdx.x;            // 0..1023
  const int xcd = bid & 7, idx = bid >> 3;
  const int b  = xcd * 16 + (idx >> 3);
  const int i0 = (idx & 7) * 64;
  const int t  = threadIdx.x;
  const int wv = t >> 6, lane = t & 63;
  const int wl = lane & 15, lg = lane >> 4;

  s2s[t] = s2g[b * Nn + t];
  s2s[256 + t] = s2g[b * Nn + 256 + t];
  const float s2m = fmaxf(fmaxf(s2m_g[4 * b], s2m_g[4 * b + 1]),
                          fmaxf(s2m_g[4 * b + 2], s2m_g[4 * b + 3]));
  const float s1v = s1g[b * Nn + i0 + wv * 16 + wl];
  const float tt = s1v + s2m;
  const float mi = fmaxf(tt, ALPHA * tt);  // lrelu monotone -> row max

  const ushort* xsrc = xbf + (size_t)b * 64 * 128 * 8;
  ushort* lt0 = &tile[0][0][0][0];
  ushort* lt1 = &tile[1][0][0][0];

  // prologue: stage round 0 into buf 0
#pragma unroll
  for (int k = 0; k < 4; ++k) {
    const int off = t + 256 * k;
    gld_lds16(xsrc + off * 8, lt0 + off * 8);
  }

  f32x4 acc[8];
#pragma unroll
  for (int f = 0; f < 8; ++f) acc[f] = (f32x4){0.f, 0.f, 0.f, 0.f};
  float lsum = 0.f;

  for (int r = 0; r < 8; ++r) {
    __syncthreads();  // compiler drains vmcnt before s_barrier: round r landed;
                      // also: all waves finished reading buf[(r+1)&1] (round r-1)
    if (r < 7) {      // stage round r+1 into the other buffer; flies during compute(r)
      const ushort* src = xsrc + (size_t)(r + 1) * 8 * 128 * 8;
      ushort* dst = ((r + 1) & 1) ? lt1 : lt0;
#pragma unroll
      for (int k = 0; k < 4; ++k) {
        const int off = t + 256 * k;
        gld_lds16(src + off * 8, dst + off * 8);
      }
    }

    const ushort* tb = (r & 1) ? lt1 : lt0;
#pragma unroll
    for (int jj = 0; jj < 2; ++jj) {
      const int jb = r * 64 + jj * 32 + 8 * lg;  // this lane's 8 consecutive j's
      float sv[8];
      *reinterpret_cast<float4*>(&sv[0]) = *reinterpret_cast<const float4*>(&s2s[jb]);
      *reinterpret_cast<float4*>(&sv[4]) = *reinterpret_cast<const float4*>(&s2s[jb + 4]);
      float p[8];
#pragma unroll
      for (int e = 0; e < 8; ++e) {
        const float t0 = s1v + sv[e];
        p[e] = __expf(fmaxf(t0, ALPHA * t0) - mi);
        lsum += p[e];
      }
      short8 af;
      unsigned* au = reinterpret_cast<unsigned*>(&af);
      au[0] = pk_bf16(p[0], p[1]); au[1] = pk_bf16(p[2], p[3]);
      au[2] = pk_bf16(p[4], p[5]); au[3] = pk_bf16(p[6], p[7]);
#pragma unroll
      for (int f = 0; f < 8; ++f) {
        const short8 bfr = *reinterpret_cast<const short8*>(
            tb + (((jj * 4 + lg) * 128 + 16 * f + wl) * 8));
        acc[f] = __builtin_amdgcn_mfma_f32_16x16x32_bf16(af, bfr, acc[f], 0, 0, 0);
      }
    }
  }

  lsum += __shfl_xor(lsum, 16);
  lsum += __shfl_xor(lsum, 32);
  if (lg == 0) lred[wv][wl] = lsum;
  __syncthreads();

  float invl[4];
#pragma unroll
  for (int qq = 0; qq < 4; ++qq) invl[qq] = 1.0f / lred[wv][lg * 4 + qq];
  const int ibase = i0 + wv * 16 + lg * 4;
  float* outb = out + (size_t)b * (Ww * Nn);
#pragma unroll
  for (int f = 0; f < 8; ++f) {
    float4 o;
    o.x = 1.f / (1.f + __expf(-(acc[f][0] * invl[0])));
    o.y = 1.f / (1.f + __expf(-(acc[f][1] * invl[1])));
    o.z = 1.f / (1.f + __expf(-(acc[f][2] * invl[2])));
    o.w = 1.f / (1.f + __expf(-(acc[f][3] * invl[3])));
    *reinterpret_cast<float4*>(outb + (16 * f + wl) * Nn + ibase) = o;
  }
}

// ---------------- fallback: round-3 fused single kernel (proven, 33.9 us) ----------------
#define TILE_OFF   0
#define TILE_BYTES (64 * 129 * 8 * 2)
#define SRED_OFF   (TILE_OFF + TILE_BYTES)
#define S1S_OFF    (SRED_OFF + 16384)
#define S2S_OFF    (S1S_OFF + 2048)
#define CVS_OFF    (S2S_OFF + 2048)
#define A1S_OFF    (CVS_OFF + 528)
#define LRED_OFF   (A1S_OFF + 512)
#define RMAX_OFF   (LRED_OFF + 1024)
#define SMEM_BYTES (RMAX_OFF + 32)

__launch_bounds__(512, 2)
__global__ void attn_fused(const float* __restrict__ x, const float* __restrict__ Wfc,
                           const float* __restrict__ bfc, const float* __restrict__ attn,
                           float* __restrict__ out) {
  extern __shared__ char smem[];
  ushort* tile = (ushort*)(smem + TILE_OFF);
  float*  sred = (float*)(smem + SRED_OFF);
  float*  s1s  = (float*)(smem + S1S_OFF);
  float*  s2s  = (float*)(smem + S2S_OFF);
  float*  cvs  = (float*)(smem + CVS_OFF);
  float*  a1s  = (float*)(smem + A1S_OFF);
  float*  lred = (float*)(smem + LRED_OFF);
  float*  rmax = (float*)(smem + RMAX_OFF);

  const int bid = blockIdx.x;
  const int xcd = bid & 7, idx = bid >> 3;
  const int b  = xcd * 16 + (idx >> 1);
  const int i0 = (idx & 1) * 256;
  const int t  = threadIdx.x;
  const int wv = t >> 6, lane = t & 63;
  const int wl = lane & 15, lg = lane >> 4;
  const float* xb = x + (size_t)b * (Ww * Nn);

  {
    const int wcol = t & 127, vq = t >> 7;
    float p = 0.f;
#pragma unroll 8
    for (int vi = 0; vi < 32; ++vi) {
      const int v = vq * 32 + vi;
      p = fmaf(attn[Ww + v], Wfc[v * Ww + wcol], p);
    }
    sred[t] = p;
    if (t < Ww) a1s[t] = attn[t];
    if (t < 64) {
      float c0p = fmaf(bfc[t], attn[Ww + t], bfc[t + 64] * attn[Ww + 64 + t]);
#pragma unroll
      for (int off = 32; off; off >>= 1) c0p += __shfl_xor(c0p, off);
      if (t == 0) cvs[Ww] = c0p;
    }
  }
  __syncthreads();
  if (t < Ww) cvs[t] = sred[t] + sred[t + 128] + sred[t + 256] + sred[t + 384];
  __syncthreads();

  const int q = t & 63;
  float s1p[8] = {0, 0, 0, 0, 0, 0, 0, 0};
  float s2p[8] = {0, 0, 0, 0, 0, 0, 0, 0};
#pragma unroll
  for (int k = 0; k < 16; ++k) {
    const int w = wv + 8 * k;
    const float aw = a1s[w];
    const float cw = cvs[w];
    const float4 lo = *reinterpret_cast<const float4*>(xb + w * Nn + 8 * q);
    const float4 hi = *reinterpret_cast<const float4*>(xb + w * Nn + 8 * q + 4);
    s1p[0] = fmaf(lo.x, aw, s1p[0]); s1p[1] = fmaf(lo.y, aw, s1p[1]);
    s1p[2] = fmaf(lo.z, aw, s1p[2]); s1p[3] = fmaf(lo.w, aw, s1p[3]);
    s1p[4] = fmaf(hi.x, aw, s1p[4]); s1p[5] = fmaf(hi.y, aw, s1p[5]);
    s1p[6] = fmaf(hi.z, aw, s1p[6]); s1p[7] = fmaf(hi.w, aw, s1p[7]);
    s2p[0] = fmaf(lo.x, cw, s2p[0]); s2p[1] = fmaf(lo.y, cw, s2p[1]);
    s2p[2] = fmaf(lo.z, cw, s2p[2]); s2p[3] = fmaf(lo.w, cw, s2p[3]);
    s2p[4] = fmaf(hi.x, cw, s2p[4]); s2p[5] = fmaf(hi.y, cw, s2p[5]);
    s2p[6] = fmaf(hi.z, cw, s2p[6]); s2p[7] = fmaf(hi.w, cw, s2p[7]);
    uint4 pk;
    pk.x = f2bf_u(lo.x) | (f2bf_u(lo.y) << 16);
    pk.y = f2bf_u(lo.z) | (f2bf_u(lo.w) << 16);
    pk.z = f2bf_u(hi.x) | (f2bf_u(hi.y) << 16);
    pk.w = f2bf_u(hi.z) | (f2bf_u(hi.w) << 16);
    *reinterpret_cast<uint4*>(tile + ((size_t)q * 129 + w) * 8) = pk;
  }

  {
    f32x4* sv = reinterpret_cast<f32x4*>(&sred[t * 8]);
    sv[0] = (f32x4){s1p[0], s1p[1], s1p[2], s1p[3]};
    sv[1] = (f32x4){s1p[4], s1p[5], s1p[6], s1p[7]};
  }
  __syncthreads();
  {
    const int qq = t >> 3, ee = t & 7;
    float a = 0.f;
#pragma unroll
    for (int g = 0; g < 8; ++g) a += sred[((g * 64) + qq) * 8 + ee];
    s1s[t] = a;
  }
  __syncthreads();
  {
    f32x4* sv = reinterpret_cast<f32x4*>(&sred[t * 8]);
    sv[0] = (f32x4){s2p[0], s2p[1], s2p[2], s2p[3]};
    sv[1] = (f32x4){s2p[4], s2p[5], s2p[6], s2p[7]};
  }
  __syncthreads();
  {
    const int qq = t >> 3, ee = t & 7;
    float d = 0.f;
#pragma unroll
    for (int g = 0; g < 8; ++g) d += sred[((g * 64) + qq) * 8 + ee];
    s2s[t] = d + cvs[Ww];
  }

  {
    float m = s2s[t];
#pragma unroll
    for (int off = 1; off < 64; off <<= 1) m = fmaxf(m, __shfl_xor(m, off));
    if (lane == 0) rmax[wv] = m;
  }
  __syncthreads();
  float s2m = rmax[0];
#pragma unroll
  for (int g = 1; g < 8; ++g) s2m = fmaxf(s2m, rmax[g]);

  float s1i[2], mi[2];
#pragma unroll
  for (int a = 0; a < 2; ++a) {
    const float s1v = s1s[i0 + wv * 32 + 16 * a + wl];
    s1i[a] = s1v;
    const float tt = s1v + s2m;
    mi[a] = fmaxf(tt, ALPHA * tt);
  }

  f32x4 acc[2][8];
#pragma unroll
  for (int a = 0; a < 2; ++a)
#pragma unroll
    for (int f = 0; f < 8; ++f) acc[a][f] = (f32x4){0.f, 0.f, 0.f, 0.f};
  float lsum0 = 0.f, lsum1 = 0.f;

  for (int jj = 0; jj < 16; ++jj) {
    const int jb = jj * 32 + 8 * lg;
    float sv[8];
    *reinterpret_cast<float4*>(&sv[0]) = *reinterpret_cast<const float4*>(&s2s[jb]);
    *reinterpret_cast<float4*>(&sv[4]) = *reinterpret_cast<const float4*>(&s2s[jb + 4]);
    short8 af0, af1;
#pragma unroll
    for (int e = 0; e < 8; ++e) {
      const float t0 = s1i[0] + sv[e];
      const float p0 = __expf(fmaxf(t0, ALPHA * t0) - mi[0]);
      lsum0 += p0;
      af0[e] = (short)f2bf_u(p0);
      const float t1 = s1i[1] + sv[e];
      const float p1 = __expf(fmaxf(t1, ALPHA * t1) - mi[1]);
      lsum1 += p1;
      af1[e] = (short)f2bf_u(p1);
    }
    const int jg = jj * 4 + lg;
#pragma unroll
    for (int f = 0; f < 8; ++f) {
      const short8 bfr = *reinterpret_cast<const short8*>(tile + ((size_t)jg * 129 + 16 * f + wl) * 8);
      acc[0][f] = __builtin_amdgcn_mfma_f32_16x16x32_bf16(af0, bfr, acc[0][f], 0, 0, 0);
      acc[1][f] = __builtin_amdgcn_mfma_f32_16x16x32_bf16(af1, bfr, acc[1][f], 0, 0, 0);
    }
  }

  lsum0 += __shfl_xor(lsum0, 16); lsum0 += __shfl_xor(lsum0, 32);
  lsum1 += __shfl_xor(lsum1, 16); lsum1 += __shfl_xor(lsum1, 32);
  if (lg == 0) { lred[wv * 32 + wl] = lsum0; lred[wv * 32 + 16 + wl] = lsum1; }
  __syncthreads();

  float* outb = out + (size_t)b * (Ww * Nn);
#pragma unroll
  for (int a = 0; a < 2; ++a) {
    float invl[4];
#pragma unroll
    for (int qq = 0; qq < 4; ++qq) invl[qq] = 1.0f / lred[wv * 32 + 16 * a + lg * 4 + qq];
    const int ibase = i0 + wv * 32 + 16 * a + lg * 4;
#pragma unroll
    for (int f = 0; f < 8; ++f) {
      float4 o;
      o.x = 1.f / (1.f + __expf(-(acc[a][f][0] * invl[0])));
      o.y = 1.f / (1.f + __expf(-(acc[a][f][1] * invl[1])));
      o.z = 1.f / (1.f + __expf(-(acc[a][f][2] * invl[2])));
      o.w = 1.f / (1.f + __expf(-(acc[a][f][3] * invl[3])));
      *reinterpret_cast<float4*>(outb + (16 * f + wl) * Nn + ibase) = o;
    }
  }
}

extern "C" void kernel_launch(void* const* d_in, const int* in_sizes, int n_in,
                              void* d_out, int out_size, void* d_ws, size_t ws_size,
                              hipStream_t stream) {
  const float* x    = (const float*)d_in[0];  // (128,128,512)
  const float* Wfc  = (const float*)d_in[1];  // (128,128)
  const float* bfc  = (const float*)d_in[2];  // (128,)
  const float* attn = (const float*)d_in[3];  // (256,1)
  float* out = (float*)d_out;                 // (128,128,512)

  char* ws = (char*)d_ws;
  const size_t XBF_BYTES = (size_t)Bb * 64 * 128 * 8 * 2;  // 16 MB
  ushort* xbf   = (ushort*)ws;
  float*  s1g   = (float*)(ws + XBF_BYTES);
  float*  s2g   = (float*)(ws + XBF_BYTES + 262144);
  float*  s2m_g = (float*)(ws + XBF_BYTES + 2 * 262144);
  const size_t NEED = XBF_BYTES + 2 * 262144 + 2048;

  if (ws_size >= NEED) {
    stream_pack<<<512, 256, 0, stream>>>(x, Wfc, bfc, attn, xbf, s1g, s2g, s2m_g);
    attn_d<<<1024, 256, 0, stream>>>(xbf, s1g, s2g, s2m_g, out);
  } else {
    (void)hipFuncSetAttribute(reinterpret_cast<const void*>(&attn_fused),
                              hipFuncAttributeMaxDynamicSharedMemorySize, SMEM_BYTES);
    attn_fused<<<256, 512, SMEM_BYTES, stream>>>(x, Wfc, bfc, attn, out);
  }
}